// Round 9
// baseline (21.092 us; speedup 1.0000x reference)
//
#include <hip/hip_runtime.h>

typedef _Float16 f16;
typedef _Float16 f16x8 __attribute__((ext_vector_type(8)));
typedef float f32x4 __attribute__((ext_vector_type(4)));

#define MFMA16(a, b, c) __builtin_amdgcn_mfma_f32_16x16x32_f16((a), (b), (c), 0, 0, 0)

// ---------------- d_ws (f16 units): fragment-linear split weights (unchanged layout) ----------------
#define WS_OBS 0        // N=64(4nt) K=128(4ch)  psz 8192
#define WS_OA  16384    // N=64(4nt) K=144->5ch  psz 10240
#define WS_K   36864    // N=64 K=64(2ch)        psz 4096
#define WS_Q   45056
#define WS_AV  53248
#define WS_F1  61440
#define WS_F2  69632    // N=16(1nt) K=64(2ch)   psz 1024
#define WS_TOT 71680    // f16 -> 143360 bytes

// ---------------- per-batch LDS arena (u16 units) ----------------
// region1 (14336): XS_HI/XS_LO (states, dead after A) overlaid by KB/QB/AAT (written in BC)
// region2 (13824): E/EA/EP -> NF/H reuse
// WM + WDIAG
#define XS_HI  0        // states split [32][136]
#define XS_LO  4352
#define KB_HI  0        // K [32][72] (overlays XS after phase A)
#define KB_LO  2304
#define QB_HI  4608
#define QB_LO  6912
#define AAT_HI 9216     // AA transposed [64][40]
#define AAT_LO 11776
#define E_HI   14336    // E [32][72] -> NF reuse
#define E_LO   16640
#define EA_HI  18944    // EA -> H reuse
#define EA_LO  21248
#define EP_HI  23552
#define EP_LO  25856
#define WM_HI  28160    // softmax w [32][40]
#define WM_LO  29440
#define WDIAG  30720    // float[32]
#define ARENA  30784
#define SMTOT  (2 * ARENA)   // 61568 u16 = 123136 B -> 1 block/CU, 8 waves

__device__ __forceinline__ void split1(float v, ushort& h, ushort& lo) {
    f16 hf = (f16)v;
    float r = v - (float)hf;
    f16 lf = (f16)r;
    union { f16 f; ushort u; } a, b;
    a.f = hf; b.f = lf;
    h = a.u; lo = b.u;
}
__device__ __forceinline__ void split4(f32x4 v, ushort4& h, ushort4& l) {
    split1(v[0], h.x, l.x);
    split1(v[1], h.y, l.y);
    split1(v[2], h.z, l.z);
    split1(v[3], h.w, l.w);
}
__device__ __forceinline__ void mk8(float4 a, float4 b, f16x8& hi, f16x8& lo) {
    float v[8] = {a.x, a.y, a.z, a.w, b.x, b.y, b.z, b.w};
    #pragma unroll
    for (int j = 0; j < 8; ++j) {
        f16 h = (f16)v[j];
        hi[j] = h;
        lo[j] = (f16)(v[j] - (float)h);
    }
}
__device__ __forceinline__ f16x8 ldf(const ushort* sm, int off) {
    return *(const f16x8*)(sm + off);
}
__device__ __forceinline__ f16x8 ldw(const f16* wsf, int base, int psz, int nch,
                                     int p, int nt, int c, int l) {
    return *(const f16x8*)(wsf + base + p * psz + (((nt * nch + c) << 6) + l) * 8);
}
__device__ __forceinline__ float fast_tanh(float x) {
    float xc = fminf(fmaxf(x, -9.0f), 9.0f);
    float e = __expf(2.0f * xc);
    return (e - 1.0f) * __builtin_amdgcn_rcpf(e + 1.0f);
}

// ---------------- prep: split weights into fragment-linear hi/lo planes (unchanged) ----------------
__global__ void prep_frags(const float* __restrict__ Wobs, const float* __restrict__ Woa,
                           const float* __restrict__ Wk,   const float* __restrict__ Wq,
                           const float* __restrict__ Wav,  const float* __restrict__ Wf1,
                           const float* __restrict__ Wf2,  f16* __restrict__ wsf) {
    int tid = blockIdx.x * 256 + threadIdx.x;   // 8960 = 2 planes x 4480 groups
    if (tid >= 8960) return;
    int p = tid >= 4480 ? 1 : 0;
    int g = tid - p * 4480;
    const float* W; int base, psz, nch, Kreal, g0;
    if (g < 1024)      { W = Wobs; base = WS_OBS; psz = 8192;  nch = 4; Kreal = 128; g0 = g; }
    else if (g < 2304) { W = Woa;  base = WS_OA;  psz = 10240; nch = 5; Kreal = 144; g0 = g - 1024; }
    else if (g < 2816) { W = Wk;   base = WS_K;   psz = 4096;  nch = 2; Kreal = 64;  g0 = g - 2304; }
    else if (g < 3328) { W = Wq;   base = WS_Q;   psz = 4096;  nch = 2; Kreal = 64;  g0 = g - 2816; }
    else if (g < 3840) { W = Wav;  base = WS_AV;  psz = 4096;  nch = 2; Kreal = 64;  g0 = g - 3328; }
    else if (g < 4352) { W = Wf1;  base = WS_F1;  psz = 4096;  nch = 2; Kreal = 64;  g0 = g - 3840; }
    else               { W = Wf2;  base = WS_F2;  psz = 1024;  nch = 2; Kreal = 64;  g0 = g - 4352; }
    int l = g0 & 63, fc = g0 >> 6;
    int c = fc % nch, nt = fc / nch;
    int o = nt * 16 + (l & 15);
    int k0 = c * 32 + (l >> 4) * 8;
    f16 out[8];
    #pragma unroll
    for (int j = 0; j < 8; ++j) {
        int k = k0 + j;
        float v = (k < Kreal) ? W[o * Kreal + k] : 0.0f;
        f16 h = (f16)v;
        out[j] = p ? (f16)(v - (float)h) : h;
    }
    *(f16x8*)(wsf + base + p * psz + g0 * 8) = *(f16x8*)out;
}

__global__ void __launch_bounds__(512, 2)
critic_mfma(const float* __restrict__ states, const float* __restrict__ policies,
            const float* __restrict__ actions, const float* __restrict__ b_obs,
            const float* __restrict__ b_oa, const f16* __restrict__ wsf,
            float* __restrict__ out_value,   // [B,32,16]
            float* __restrict__ out_weight)  // [B,32,32]
{
    __shared__ ushort smraw[SMTOT];
    const int t = threadIdx.x;
    const int wv = t >> 6, l = t & 63;
    const int bt = t >> 8;             // batch half 0/1 (waves 0-3 / 4-7)
    const int tb = t & 255;            // thread-in-batch
    const int ft = wv & 3;             // feature tile within batch
    const int lr = l & 15;
    const int lg = l >> 4;
    const int f0 = ft * 16 + lg * 4;
    const int b = blockIdx.x * 2 + bt;
    ushort* sm = smraw + bt * ARENA;

    // ---- issue states loads first ----
    float4 sv[4];
    {
        const float4* src = (const float4*)(states + (size_t)b * 4096);
        #pragma unroll
        for (int r4 = 0; r4 < 4; ++r4) sv[r4] = src[tb + r4 * 256];
    }

    // ---- prefetch phase-A weight fragments (L2) ----
    f16x8 wObsH[4], wObsL[4], wOaH[4], wOaL[4];
    #pragma unroll
    for (int c = 0; c < 4; ++c) {
        wObsH[c] = ldw(wsf, WS_OBS, 8192, 4, 0, ft, c, l);
        wObsL[c] = ldw(wsf, WS_OBS, 8192, 4, 1, ft, c, l);
        wOaH[c]  = ldw(wsf, WS_OA, 10240, 5, 0, ft, c, l);
        wOaL[c]  = ldw(wsf, WS_OA, 10240, 5, 1, ft, c, l);
    }
    f16x8 wTailH = ldw(wsf, WS_OA, 10240, 5, 0, ft, 4, l);
    f16x8 wTailL = ldw(wsf, WS_OA, 10240, 5, 1, ft, 4, l);

    // ---- act/pol tail B-fragments in-register (k>=16 zero) ----
    f16x8 actH[2], actL[2], polH[2], polL[2];
    #pragma unroll
    for (int at = 0; at < 2; ++at) {
        float4 a0v = make_float4(0.f, 0.f, 0.f, 0.f), a1v = a0v, p0v = a0v, p1v = a0v;
        if (lg < 2) {
            size_t base = (size_t)b * 512 + (at * 16 + lr) * 16 + lg * 8;
            a0v = *(const float4*)(actions + base);
            a1v = *(const float4*)(actions + base + 4);
            p0v = *(const float4*)(policies + base);
            p1v = *(const float4*)(policies + base + 4);
        }
        mk8(a0v, a1v, actH[at], actL[at]);
        mk8(p0v, p1v, polH[at], polL[at]);
    }

    // ---- stage states split hi/lo into LDS ----
    #pragma unroll
    for (int r4 = 0; r4 < 4; ++r4) {
        int e4 = tb + r4 * 256, row = e4 >> 5, k0 = (e4 & 31) * 4;
        ushort4 h, lo;
        split1(sv[r4].x, h.x, lo.x);
        split1(sv[r4].y, h.y, lo.y);
        split1(sv[r4].z, h.z, lo.z);
        split1(sv[r4].w, h.w, lo.w);
        *(ushort4*)(sm + XS_HI + row * 136 + k0) = h;
        *(ushort4*)(sm + XS_LO + row * 136 + k0) = lo;
    }
    __syncthreads();

    const f32x4 Z = {0.f, 0.f, 0.f, 0.f};

    // ================= phase A: E = relu(S@WobsT+b); EA/EP = relu(S@WoaT + tail + b) =================
    // even/odd-chunk split accumulators: 8 independent MFMA chains
    f32x4 accEa[2] = {Z, Z}, accEb[2] = {Z, Z}, accPa[2] = {Z, Z}, accPb[2] = {Z, Z};
    #pragma unroll
    for (int c = 0; c < 4; ++c) {
        #pragma unroll
        for (int at = 0; at < 2; ++at) {
            int ao = (at * 16 + lr) * 136 + c * 32 + lg * 8;
            f16x8 xh = ldf(sm, XS_HI + ao), xl = ldf(sm, XS_LO + ao);
            if ((c & 1) == 0) {
                accEa[at] = MFMA16(wObsH[c], xh, accEa[at]);
                accEa[at] = MFMA16(wObsH[c], xl, accEa[at]);
                accEa[at] = MFMA16(wObsL[c], xh, accEa[at]);
                accPa[at] = MFMA16(wOaH[c], xh, accPa[at]);
                accPa[at] = MFMA16(wOaH[c], xl, accPa[at]);
                accPa[at] = MFMA16(wOaL[c], xh, accPa[at]);
            } else {
                accEb[at] = MFMA16(wObsH[c], xh, accEb[at]);
                accEb[at] = MFMA16(wObsH[c], xl, accEb[at]);
                accEb[at] = MFMA16(wObsL[c], xh, accEb[at]);
                accPb[at] = MFMA16(wOaH[c], xh, accPb[at]);
                accPb[at] = MFMA16(wOaH[c], xl, accPb[at]);
                accPb[at] = MFMA16(wOaL[c], xh, accPb[at]);
            }
        }
    }
    f32x4 accE[2], accEA[2], accEP[2];
    #pragma unroll
    for (int at = 0; at < 2; ++at) {
        accE[at] = accEa[at] + accEb[at];
        f32x4 base = accPa[at] + accPb[at];
        accEA[at] = base;
        accEP[at] = base;
        accEA[at] = MFMA16(wTailH, actH[at], accEA[at]);
        accEA[at] = MFMA16(wTailH, actL[at], accEA[at]);
        accEA[at] = MFMA16(wTailL, actH[at], accEA[at]);
        accEP[at] = MFMA16(wTailH, polH[at], accEP[at]);
        accEP[at] = MFMA16(wTailH, polL[at], accEP[at]);
        accEP[at] = MFMA16(wTailL, polH[at], accEP[at]);
    }

    // prefetch phase-BC weights while A finishes
    f16x8 wKH[2], wKL[2], wQH[2], wQL[2], wVH[2], wVL[2];
    #pragma unroll
    for (int c = 0; c < 2; ++c) {
        wKH[c] = ldw(wsf, WS_K, 4096, 2, 0, ft, c, l);
        wKL[c] = ldw(wsf, WS_K, 4096, 2, 1, ft, c, l);
        wQH[c] = ldw(wsf, WS_Q, 4096, 2, 0, ft, c, l);
        wQL[c] = ldw(wsf, WS_Q, 4096, 2, 1, ft, c, l);
        wVH[c] = ldw(wsf, WS_AV, 4096, 2, 0, ft, c, l);
        wVL[c] = ldw(wsf, WS_AV, 4096, 2, 1, ft, c, l);
    }

    {
        float4 bo = *(const float4*)&b_obs[f0];
        float4 ba = *(const float4*)&b_oa[f0];
        #pragma unroll
        for (int at = 0; at < 2; ++at) {
            int agent = at * 16 + lr;
            f32x4 e, ea, ep;
            e[0] = fmaxf(accE[at][0] + bo.x, 0.f);  e[1] = fmaxf(accE[at][1] + bo.y, 0.f);
            e[2] = fmaxf(accE[at][2] + bo.z, 0.f);  e[3] = fmaxf(accE[at][3] + bo.w, 0.f);
            ea[0] = fmaxf(accEA[at][0] + ba.x, 0.f); ea[1] = fmaxf(accEA[at][1] + ba.y, 0.f);
            ea[2] = fmaxf(accEA[at][2] + ba.z, 0.f); ea[3] = fmaxf(accEA[at][3] + ba.w, 0.f);
            ep[0] = fmaxf(accEP[at][0] + ba.x, 0.f); ep[1] = fmaxf(accEP[at][1] + ba.y, 0.f);
            ep[2] = fmaxf(accEP[at][2] + ba.z, 0.f); ep[3] = fmaxf(accEP[at][3] + ba.w, 0.f);
            ushort4 h, lo;
            split4(e, h, lo);
            *(ushort4*)(sm + E_HI + agent * 72 + f0) = h;
            *(ushort4*)(sm + E_LO + agent * 72 + f0) = lo;
            split4(ea, h, lo);
            *(ushort4*)(sm + EA_HI + agent * 72 + f0) = h;
            *(ushort4*)(sm + EA_LO + agent * 72 + f0) = lo;
            split4(ep, h, lo);
            *(ushort4*)(sm + EP_HI + agent * 72 + f0) = h;
            *(ushort4*)(sm + EP_LO + agent * 72 + f0) = lo;
        }
    }
    __syncthreads();

    // ================= phase BC: K=E@WkT, Q=E@WqT, AA/AP=tanh(EA/EP@WavT) =================
    f32x4 dDiff[2];
    {
        f32x4 aK[2] = {Z, Z}, aQ[2] = {Z, Z}, aA[2] = {Z, Z}, aP[2] = {Z, Z};
        #pragma unroll
        for (int c = 0; c < 2; ++c) {
            #pragma unroll
            for (int at = 0; at < 2; ++at) {
                int ao = (at * 16 + lr) * 72 + c * 32 + lg * 8;
                f16x8 eh = ldf(sm, E_HI + ao),  el = ldf(sm, E_LO + ao);
                f16x8 xh = ldf(sm, EA_HI + ao), xl = ldf(sm, EA_LO + ao);
                f16x8 yh = ldf(sm, EP_HI + ao), yl = ldf(sm, EP_LO + ao);
                aK[at] = MFMA16(wKH[c], eh, aK[at]);
                aK[at] = MFMA16(wKH[c], el, aK[at]);
                aK[at] = MFMA16(wKL[c], eh, aK[at]);
                aQ[at] = MFMA16(wQH[c], eh, aQ[at]);
                aQ[at] = MFMA16(wQH[c], el, aQ[at]);
                aQ[at] = MFMA16(wQL[c], eh, aQ[at]);
                aA[at] = MFMA16(wVH[c], xh, aA[at]);
                aA[at] = MFMA16(wVH[c], xl, aA[at]);
                aA[at] = MFMA16(wVL[c], xh, aA[at]);
                aP[at] = MFMA16(wVH[c], yh, aP[at]);
                aP[at] = MFMA16(wVH[c], yl, aP[at]);
                aP[at] = MFMA16(wVL[c], yh, aP[at]);
            }
        }
        #pragma unroll
        for (int at = 0; at < 2; ++at) {
            int agent = at * 16 + lr;
            ushort4 h, lo;
            split4(aK[at], h, lo);
            *(ushort4*)(sm + KB_HI + agent * 72 + f0) = h;
            *(ushort4*)(sm + KB_LO + agent * 72 + f0) = lo;
            split4(aQ[at], h, lo);
            *(ushort4*)(sm + QB_HI + agent * 72 + f0) = h;
            *(ushort4*)(sm + QB_LO + agent * 72 + f0) = lo;
            f32x4 ta, tp;
            #pragma unroll
            for (int r = 0; r < 4; ++r) {
                ta[r] = fast_tanh(aA[at][r]);
                tp[r] = fast_tanh(aP[at][r]);
            }
            dDiff[at] = tp - ta;
            #pragma unroll
            for (int r = 0; r < 4; ++r) {      // AA transposed (phase-D A-operand)
                ushort hh, ll;
                split1(ta[r], hh, ll);
                sm[AAT_HI + (f0 + r) * 40 + agent] = hh;
                sm[AAT_LO + (f0 + r) * 40 + agent] = ll;
            }
        }
    }

    // prefetch phase-E/F weights
    f16x8 wF1H[2], wF1L[2], wF2H[2], wF2L[2];
    #pragma unroll
    for (int c = 0; c < 2; ++c) {
        wF1H[c] = ldw(wsf, WS_F1, 4096, 2, 0, ft, c, l);
        wF1L[c] = ldw(wsf, WS_F1, 4096, 2, 1, ft, c, l);
    }
    if (ft < 2) {
        #pragma unroll
        for (int c = 0; c < 2; ++c) {
            wF2H[c] = ldw(wsf, WS_F2, 1024, 2, 0, 0, c, l);
            wF2L[c] = ldw(wsf, WS_F2, 1024, 2, 1, 0, c, l);
        }
    }
    __syncthreads();

    // ================= score + softmax (ft 0,1 waves of each batch) =================
    if (ft < 2) {
        int jt = ft;
        f16x8 kh[2], kl[2];
        #pragma unroll
        for (int c = 0; c < 2; ++c) {
            int ko = (jt * 16 + lr) * 72 + c * 32 + lg * 8;
            kh[c] = ldf(sm, KB_HI + ko);
            kl[c] = ldf(sm, KB_LO + ko);
        }
        f32x4 s[2] = {Z, Z};
        #pragma unroll
        for (int c = 0; c < 2; ++c) {
            #pragma unroll
            for (int it = 0; it < 2; ++it) {
                int qo = (it * 16 + lr) * 72 + c * 32 + lg * 8;
                f16x8 qh = ldf(sm, QB_HI + qo), ql = ldf(sm, QB_LO + qo);
                s[it] = MFMA16(kh[c], qh, s[it]);
                s[it] = MFMA16(kh[c], ql, s[it]);
                s[it] = MFMA16(kl[c], qh, s[it]);
            }
        }
        float* wdiag = (float*)(sm + WDIAG);
        #pragma unroll
        for (int r = 0; r < 4; ++r) {
            int j = jt * 16 + lg * 4 + r;
            float v0 = s[0][r] * 0.125f, v1 = s[1][r] * 0.125f;
            float m = fmaxf(v0, v1);
            #pragma unroll
            for (int off = 1; off < 16; off <<= 1)
                m = fmaxf(m, __shfl_xor(m, off, 16));
            float e0 = __expf(v0 - m), e1 = __expf(v1 - m);
            float su = e0 + e1;
            #pragma unroll
            for (int off = 1; off < 16; off <<= 1)
                su += __shfl_xor(su, off, 16);
            float inv = 1.0f / su;
            e0 *= inv; e1 *= inv;
            out_weight[(size_t)b * 1024 + j * 32 + lr] = e0;
            out_weight[(size_t)b * 1024 + j * 32 + 16 + lr] = e1;
            ushort hh, ll;
            split1(e0, hh, ll);
            sm[WM_HI + j * 40 + lr] = hh;
            sm[WM_LO + j * 40 + lr] = ll;
            split1(e1, hh, ll);
            sm[WM_HI + j * 40 + 16 + lr] = hh;
            sm[WM_LO + j * 40 + 16 + lr] = ll;
            if (lr == lg * 4 + r) wdiag[j] = jt ? e1 : e0;
        }
    }
    __syncthreads();

    // ================= phase D: NF[j][f] = (1/32)(sum_i w[j,i]AA[i,f] + w[j,j](AP-AA)[j,f]) =================
    {
        int fo = (ft * 16 + lr) * 40 + lg * 8;
        f16x8 ah = ldf(sm, AAT_HI + fo);
        f16x8 al = ldf(sm, AAT_LO + fo);
        const float* wdiag = (const float*)(sm + WDIAG);
        #pragma unroll
        for (int jt = 0; jt < 2; ++jt) {
            int j = jt * 16 + lr;
            f16x8 wh = ldf(sm, WM_HI + j * 40 + lg * 8);
            f16x8 wl = ldf(sm, WM_LO + j * 40 + lg * 8);
            f32x4 acc = Z;
            acc = MFMA16(ah, wh, acc);
            acc = MFMA16(ah, wl, acc);
            acc = MFMA16(al, wh, acc);
            float wd = wdiag[j];
            f32x4 nf;
            #pragma unroll
            for (int r = 0; r < 4; ++r)
                nf[r] = (acc[r] + wd * dDiff[jt][r]) * 0.03125f;
            ushort4 h, lo;
            split4(nf, h, lo);
            *(ushort4*)(sm + E_HI + j * 72 + f0) = h;   // NF overwrites E (dead)
            *(ushort4*)(sm + E_LO + j * 72 + f0) = lo;
        }
    }
    __syncthreads();

    // ================= phase E: H = leaky_relu(NF @ Wf1T) =================
    {
        f32x4 hA[2] = {Z, Z};
        #pragma unroll
        for (int c = 0; c < 2; ++c) {
            #pragma unroll
            for (int jt = 0; jt < 2; ++jt) {
                int bo2 = (jt * 16 + lr) * 72 + c * 32 + lg * 8;
                f16x8 nh_ = ldf(sm, E_HI + bo2), nl_ = ldf(sm, E_LO + bo2);
                hA[jt] = MFMA16(wF1H[c], nh_, hA[jt]);
                hA[jt] = MFMA16(wF1H[c], nl_, hA[jt]);
                hA[jt] = MFMA16(wF1L[c], nh_, hA[jt]);
            }
        }
        #pragma unroll
        for (int jt = 0; jt < 2; ++jt) {
            int j = jt * 16 + lr;
            f32x4 hv;
            #pragma unroll
            for (int r = 0; r < 4; ++r)
                hv[r] = fmaxf(hA[jt][r], 0.01f * hA[jt][r]);
            ushort4 h, lo;
            split4(hv, h, lo);
            *(ushort4*)(sm + EA_HI + j * 72 + f0) = h;  // H overwrites EA (dead)
            *(ushort4*)(sm + EA_LO + j * 72 + f0) = lo;
        }
    }
    __syncthreads();

    // ================= phase F (ft 0,1 waves): value = H @ Wf2T =================
    if (ft < 2) {
        int jt = ft;
        f32x4 acc = Z;
        #pragma unroll
        for (int c = 0; c < 2; ++c) {
            int ho = (jt * 16 + lr) * 72 + c * 32 + lg * 8;
            f16x8 hh = ldf(sm, EA_HI + ho), hl = ldf(sm, EA_LO + ho);
            acc = MFMA16(wF2H[c], hh, acc);
            acc = MFMA16(wF2H[c], hl, acc);
            acc = MFMA16(wF2L[c], hh, acc);
        }
        int j = jt * 16 + lr;
        *(float4*)&out_value[(size_t)b * 512 + j * 16 + lg * 4] =
            make_float4(acc[0], acc[1], acc[2], acc[3]);
    }
}

extern "C" void kernel_launch(void* const* d_in, const int* in_sizes, int n_in,
                              void* d_out, int out_size, void* d_ws, size_t ws_size,
                              hipStream_t stream) {
    const float* states   = (const float*)d_in[0];
    const float* policies = (const float*)d_in[1];
    const float* actions  = (const float*)d_in[2];
    const float* W_obs    = (const float*)d_in[3];
    const float* b_obs    = (const float*)d_in[4];
    const float* W_oa     = (const float*)d_in[5];
    const float* b_oa     = (const float*)d_in[6];
    const float* W_key    = (const float*)d_in[7];
    const float* W_query  = (const float*)d_in[8];
    const float* W_av     = (const float*)d_in[9];
    const float* W_f1     = (const float*)d_in[10];
    const float* W_f2     = (const float*)d_in[11];

    f16* wsf = (f16*)d_ws;
    float* out_value  = (float*)d_out;                 // [512,32,16]
    float* out_weight = (float*)d_out + 512 * 32 * 16; // [512,32,32]

    prep_frags<<<35, 256, 0, stream>>>(W_obs, W_oa, W_key, W_query, W_av, W_f1, W_f2, wsf);
    critic_mfma<<<256, 512, 0, stream>>>(states, policies, actions,
                                         b_obs, b_oa, wsf, out_value, out_weight);
}